// Round 3
// baseline (2310.056 us; speedup 1.0000x reference)
//
#include <hip/hip_runtime.h>
#include <stdint.h>

// NeighborWiseAttention fused kernel: 1 workgroup = 1 batch element, both layers fused.
// B=4096, NNEI=128, EMBED=64, HIDDEN=128, NLAYER=2.
// All matmuls via v_mfma_f32_16x16x32_bf16; softmax/LN/norm-scales in f32.
// R2: weights pre-converted to bf16 + pre-transposed into d_ws by prep kernel.
// R3: waves_per_eu(2,2) to unlock 256 VGPRs (anti-spill); woT staged to LDS
//     (bufV reuse) before M4; final store via xs re-gather as float4.

typedef float f32x4 __attribute__((ext_vector_type(4)));
typedef short bf16x8 __attribute__((ext_vector_type(8)));
typedef unsigned short ushort4v __attribute__((ext_vector_type(4)));

#define MFMA(a, b, c) __builtin_amdgcn_mfma_f32_16x16x32_bf16(a, b, c, 0, 0, 0)

#define SCALING 0.08838834764831845f  // HIDDEN^-0.5
#define SHIFTW 20.0f

// d_ws map (bytes):
//   wiT bf16 [2][384][64]  @ 0       98304   (wiT[l][c][k] = in_w[l][k][c])
//   woT bf16 [2][64][128]  @ 98304   32768   (woT[l][e][k] = out_w[l][k][e])

// LDS map (bytes):
//   xs   f32 [128][64]   @ 0       32768   (x, f32 for residual/LN)
//   xbf  bf16[128][64]   @ 32768   16384   (x, bf16 MFMA copy)
//   bufA bf16[128][128]  @ 49152   32768   (raw q  -> later o)
//   bufB bf16[128][128]  @ 81920   32768   (raw k  -> later P)
//   bufV bf16[128][128]  @ 114688  32768   (raw v^T: [h][m] -> later woT LDS copy)
//   sml  f32 [2048]      @ 147456  8192    (sw,mask,rx,ry,rz,qs,ks,vs,vpart[8][128])
#define XS_OFF   0
#define XBF_OFF  32768
#define BA_OFF   49152
#define BB_OFF   81920
#define VT_OFF   114688
#define SM_OFF   147456
#define SMEM_BYTES 155648

__device__ __forceinline__ float bf2f(unsigned short u) {
    union { unsigned int u; float f; } v; v.u = ((unsigned int)u) << 16; return v.f;
}
__device__ __forceinline__ unsigned short f2bf(float f) {
    union { float f; unsigned int u; } v; v.f = f;
    unsigned int r = v.u + 0x7FFFu + ((v.u >> 16) & 1u);  // RNE
    return (unsigned short)(r >> 16);
}

// ---- prep: convert+transpose weights to bf16 in d_ws ----
__global__ void prep_weights(const float* __restrict__ in_w,
                             const float* __restrict__ out_w,
                             unsigned short* __restrict__ ws) {
    unsigned short* wiT = ws;                       // [2][384][64]
    unsigned short* woT = ws + 49152;               // [2][64][128]
    const int gid = blockIdx.x * blockDim.x + threadIdx.x;
    for (int i = gid; i < 49152; i += gridDim.x * blockDim.x) {
        const int l = i / 24576, rem = i % 24576;
        const int c = rem / 64, k = rem % 64;
        wiT[i] = f2bf(in_w[l * 24576 + k * 384 + c]);
    }
    for (int j = gid; j < 16384; j += gridDim.x * blockDim.x) {
        const int l = j / 8192, rem = j % 8192;
        const int e = rem / 128, k = rem % 128;
        woT[j] = f2bf(out_w[l * 8192 + k * 64 + e]);
    }
}

__global__ __launch_bounds__(512) __attribute__((amdgpu_waves_per_eu(2, 2)))
void nwa_kernel(const float* __restrict__ G, const int* __restrict__ nmask,
                const float* __restrict__ rvec, const float* __restrict__ swg,
                const unsigned short* __restrict__ wsw,
                const float* __restrict__ in_b,
                const float* __restrict__ out_b,
                const float* __restrict__ ln_g, const float* __restrict__ ln_b,
                float* __restrict__ out)
{
    extern __shared__ __align__(16) char smem[];
    float* xs            = (float*)(smem + XS_OFF);
    unsigned short* xbf  = (unsigned short*)(smem + XBF_OFF);
    unsigned short* bufA = (unsigned short*)(smem + BA_OFF);
    unsigned short* bufB = (unsigned short*)(smem + BB_OFF);
    unsigned short* bufV = (unsigned short*)(smem + VT_OFF);
    float* sml = (float*)(smem + SM_OFF);
    float* SW = sml;        float* MK = sml + 128;  float* RX = sml + 256;
    float* RY = sml + 384;  float* RZ = sml + 512;  float* QS = sml + 640;
    float* KS = sml + 768;  float* VS = sml + 896;  float* VP = sml + 1024;

    const int b    = blockIdx.x;
    const int tid  = threadIdx.x;
    const int w    = tid >> 6;     // wave 0..7
    const int lane = tid & 63;
    const int lg   = lane >> 4;    // 0..3
    const int lr   = lane & 15;    // 0..15

    // ---- stage x (f32 + bf16, swizzled), float4 loads ----
    const float* Gp = G + (size_t)b * 8192;
    for (int i = tid; i < 2048; i += 512) {        // 2048 float4s
        f32x4 v = ((const f32x4*)Gp)[i];
        const int r  = i >> 4;                     // 16 float4 per 64-wide row
        const int e4 = (i & 15) << 2;              // first element col (4-aligned)
        const int se = e4 ^ ((r & 7) << 3);        // swizzle preserves 4-alignment
        *(f32x4*)(xs + (r << 6) + se) = v;
        ushort4v h = { f2bf(v[0]), f2bf(v[1]), f2bf(v[2]), f2bf(v[3]) };
        *(ushort4v*)(xbf + (r << 6) + se) = h;
    }
    if (tid < 128) {
        SW[tid] = swg[(size_t)b * 128 + tid];
        MK[tid] = nmask[(size_t)b * 128 + tid] ? 1.0f : 0.0f;
        const float* rp = rvec + ((size_t)b * 128 + tid) * 3;
        RX[tid] = rp[0]; RY[tid] = rp[1]; RZ[tid] = rp[2];
    }
    __syncthreads();

    for (int l = 0; l < 2; ++l) {
        const unsigned short* wiT = wsw + l * 24576;          // bf16 [384][64]
        const unsigned short* woT = wsw + 49152 + l * 8192;   // bf16 [64][128]
        const float* bi  = in_b  + l * 384;
        const float* bo  = out_b + l * 64;
        const float* lgp = ln_g  + l * 64;
        const float* lbp = ln_b  + l * 64;

        // ---- M1: qkv = x @ wi + bi ; write raw q->bufA, k->bufB, v^T->bufV ----
        #pragma unroll 1
        for (int cc = 0; cc < 3; ++cc) {
            const int ct = w * 3 + cc;       // 0..23 column tile
            const int c  = ct * 16 + lr;     // 0..383
            bf16x8 b0 = *(const bf16x8*)(wiT + c * 64 + lg * 8);
            bf16x8 b1 = *(const bf16x8*)(wiT + c * 64 + 32 + lg * 8);
            const float bias = bi[c];
            const int sel = ct >> 3;         // 0=q 1=k 2=v
            const int cl  = c & 127;
            #pragma unroll
            for (int rt = 0; rt < 8; ++rt) {
                const int ar = rt * 16 + lr;
                bf16x8 a0 = *(const bf16x8*)(smem + XBF_OFF + (ar << 7) + (((lg << 4)      ) ^ ((ar & 7) << 4)));
                bf16x8 a1 = *(const bf16x8*)(smem + XBF_OFF + (ar << 7) + (((lg << 4) + 64 ) ^ ((ar & 7) << 4)));
                f32x4 acc = { bias, bias, bias, bias };
                acc = MFMA(a0, b0, acc);
                acc = MFMA(a1, b1, acc);
                #pragma unroll
                for (int i = 0; i < 4; ++i) {
                    const int r = rt * 16 + lg * 4 + i;
                    unsigned short hv = f2bf(acc[i]);
                    if (sel == 0)      bufA[(r << 7) + (cl ^ ((r & 7) << 3))] = hv;
                    else if (sel == 1) bufB[(r << 7) + (cl ^ ((r & 7) << 3))] = hv;
                    else               bufV[(cl << 7) + (r ^ ((cl & 7) << 3))] = hv;  // transposed
                }
            }
        }
        __syncthreads();

        // ---- row-norm scales: qs = SCALING/||q||, ks = 1/||k||, vs = 1/||v|| ----
        {
            unsigned short* buf = (w >= 4) ? bufB : bufA;
            float* outs = (w >= 4) ? KS : QS;
            const float mul = (w >= 4) ? 1.0f : SCALING;
            #pragma unroll 1
            for (int it = 0; it < 32; ++it) {
                const int r = (w & 3) * 32 + it;
                unsigned int u = *(const unsigned int*)(buf + (r << 7) + ((lane << 1) ^ ((r & 7) << 3)));
                float v0 = bf2f((unsigned short)(u & 0xFFFFu));
                float v1 = bf2f((unsigned short)(u >> 16));
                float ss = v0 * v0 + v1 * v1;
                #pragma unroll
                for (int d = 1; d < 64; d <<= 1) ss += __shfl_xor(ss, d, 64);
                if (lane == 0) outs[r] = mul / fmaxf(sqrtf(ss), 1e-12f);
            }
            float p0 = 0.f, p1 = 0.f;    // v column sums over bufV rows (= v row norms)
            #pragma unroll 1
            for (int it = 0; it < 16; ++it) {
                const int h = w * 16 + it;
                float a  = bf2f(bufV[(h << 7) + ( lane       ^ ((h & 7) << 3))]);
                float c2 = bf2f(bufV[(h << 7) + ((lane + 64) ^ ((h & 7) << 3))]);
                p0 += a * a; p1 += c2 * c2;
            }
            VP[w * 128 + lane]      = p0;
            VP[w * 128 + lane + 64] = p1;
        }
        __syncthreads();
        if (tid < 128) {
            float s = 0.f;
            #pragma unroll
            for (int k = 0; k < 8; ++k) s += VP[k * 128 + tid];
            VS[tid] = 1.0f / fmaxf(sqrtf(s), 1e-12f);
        }
        __syncthreads();

        // ---- M2: S = q @ k^T (raw), then in-register gated softmax ----
        const int rt = w;   // wave owns rows rt*16..rt*16+15
        float P[8][4];
        {
            bf16x8 aq[4];
            #pragma unroll
            for (int kt = 0; kt < 4; ++kt) {
                const int ar = rt * 16 + lr;
                aq[kt] = *(const bf16x8*)(smem + BA_OFF + (ar << 8) + (((kt << 6) + (lg << 4)) ^ ((ar & 7) << 4)));
            }
            #pragma unroll
            for (int mt = 0; mt < 8; ++mt) {
                f32x4 acc = { 0.f, 0.f, 0.f, 0.f };
                #pragma unroll
                for (int kt = 0; kt < 4; ++kt) {
                    const int br = mt * 16 + lr;
                    bf16x8 bk = *(const bf16x8*)(smem + BB_OFF + (br << 8) + (((kt << 6) + (lg << 4)) ^ ((br & 7) << 4)));
                    acc = MFMA(aq[kt], bk, acc);
                }
                P[mt][0] = acc[0]; P[mt][1] = acc[1]; P[mt][2] = acc[2]; P[mt][3] = acc[3];
            }
        }
        float qs_i[4], swr[4], mkr[4], rxr[4], ryr[4], rzr[4];
        #pragma unroll
        for (int i = 0; i < 4; ++i) {
            const int r = rt * 16 + lg * 4 + i;
            qs_i[i] = QS[r]; swr[i] = SW[r]; mkr[i] = MK[r];
            rxr[i] = RX[r];  ryr[i] = RY[r]; rzr[i] = RZ[r];
        }
        float mx[4] = { -1e30f, -1e30f, -1e30f, -1e30f };
        #pragma unroll
        for (int mt = 0; mt < 8; ++mt) {
            const int m = mt * 16 + lr;
            const float ksm = KS[m], swm = SW[m];
            #pragma unroll
            for (int i = 0; i < 4; ++i) {
                float Lv = (P[mt][i] * qs_i[i] * ksm + SHIFTW) * (swr[i] * swm) - SHIFTW;
                P[mt][i] = Lv;
                mx[i] = fmaxf(mx[i], Lv);
            }
        }
        #pragma unroll
        for (int i = 0; i < 4; ++i) {
            #pragma unroll
            for (int d = 1; d < 16; d <<= 1) mx[i] = fmaxf(mx[i], __shfl_xor(mx[i], d, 64));
        }
        float smv[4] = { 0.f, 0.f, 0.f, 0.f };
        #pragma unroll
        for (int mt = 0; mt < 8; ++mt) {
            #pragma unroll
            for (int i = 0; i < 4; ++i) {
                float e = __expf(P[mt][i] - mx[i]);
                P[mt][i] = e; smv[i] += e;
            }
        }
        #pragma unroll
        for (int i = 0; i < 4; ++i) {
            #pragma unroll
            for (int d = 1; d < 16; d <<= 1) smv[i] += __shfl_xor(smv[i], d, 64);
            smv[i] = 1.0f / smv[i];
        }
        #pragma unroll
        for (int mt = 0; mt < 8; ++mt) {
            const int m = mt * 16 + lr;
            const float swm = SW[m], rxm = RX[m], rym = RY[m], rzm = RZ[m], vsm = VS[m];
            #pragma unroll
            for (int i = 0; i < 4; ++i) {
                float ang = rxr[i] * rxm + ryr[i] * rym + rzr[i] * rzm;
                P[mt][i] = P[mt][i] * smv[i] * mkr[i] * (swr[i] * swm) * ang * vsm;
            }
        }
        __syncthreads();   // all waves done reading bufB(k) before P overwrites it
        #pragma unroll
        for (int mt = 0; mt < 8; ++mt) {
            const int m = mt * 16 + lr;
            #pragma unroll
            for (int i = 0; i < 4; ++i) {
                const int r = rt * 16 + lg * 4 + i;
                bufB[(r << 7) + (m ^ ((r & 7) << 3))] = f2bf(P[mt][i]);
            }
        }
        __syncthreads();

        // ---- M3: o = P @ v  (B-operand = A-style read of v^T) ----
        f32x4 oacc[8];
        {
            bf16x8 ap[4];
            #pragma unroll
            for (int kt = 0; kt < 4; ++kt) {
                const int ar = rt * 16 + lr;
                ap[kt] = *(const bf16x8*)(smem + BB_OFF + (ar << 8) + (((kt << 6) + (lg << 4)) ^ ((ar & 7) << 4)));
            }
            #pragma unroll
            for (int nt = 0; nt < 8; ++nt) {
                oacc[nt] = (f32x4){ 0.f, 0.f, 0.f, 0.f };
                #pragma unroll
                for (int kt = 0; kt < 4; ++kt) {
                    const int br = nt * 16 + lr;
                    bf16x8 bv = *(const bf16x8*)(smem + VT_OFF + (br << 8) + (((kt << 6) + (lg << 4)) ^ ((br & 7) << 4)));
                    oacc[nt] = MFMA(ap[kt], bv, oacc[nt]);
                }
            }
        }
        __syncthreads();   // reads of bufV(v)/bufB(P) done; bufV now reusable

        // write o -> bufA, and stage woT(16KB) -> bufV (kills 8x-redundant global reads)
        #pragma unroll
        for (int nt = 0; nt < 8; ++nt) {
            const int hcol = nt * 16 + lr;
            #pragma unroll
            for (int i = 0; i < 4; ++i) {
                const int r = rt * 16 + lg * 4 + i;
                bufA[(r << 7) + (hcol ^ ((r & 7) << 3))] = f2bf(oacc[nt][i]);
            }
        }
        {
            const int e  = tid >> 3;          // 0..63
            const int k0 = (tid & 7) << 4;    // 0,16,..,112
            bf16x8 w0 = *(const bf16x8*)(woT + e * 128 + k0);
            bf16x8 w1 = *(const bf16x8*)(woT + e * 128 + k0 + 8);
            *(bf16x8*)(smem + VT_OFF + (e << 8) + (((k0 << 1)     ) ^ ((e & 7) << 4))) = w0;
            *(bf16x8*)(smem + VT_OFF + (e << 8) + (((k0 << 1) + 16) ^ ((e & 7) << 4))) = w1;
        }
        __syncthreads();

        // ---- M4: out = o @ out_w + out_b ; residual + LayerNorm ----
        {
            bf16x8 ao[4];
            #pragma unroll
            for (int kt = 0; kt < 4; ++kt) {
                const int ar = rt * 16 + lr;
                ao[kt] = *(const bf16x8*)(smem + BA_OFF + (ar << 8) + (((kt << 6) + (lg << 4)) ^ ((ar & 7) << 4)));
            }
            f32x4 acc4[4];
            #pragma unroll
            for (int nt = 0; nt < 4; ++nt) {
                const int e = nt * 16 + lr;
                const float bias = bo[e];
                acc4[nt] = (f32x4){ bias, bias, bias, bias };
                #pragma unroll
                for (int kt = 0; kt < 4; ++kt) {
                    bf16x8 bw = *(const bf16x8*)(smem + VT_OFF + (e << 8) + ((((kt << 6) + (lg << 4))) ^ ((e & 7) << 4)));
                    acc4[nt] = MFMA(ao[kt], bw, acc4[nt]);
                }
            }
            float gg[4], bb2[4];
            #pragma unroll
            for (int nt = 0; nt < 4; ++nt) { gg[nt] = lgp[nt * 16 + lr]; bb2[nt] = lbp[nt * 16 + lr]; }
            #pragma unroll
            for (int i = 0; i < 4; ++i) {
                const int r = rt * 16 + lg * 4 + i;
                float y[4]; float s1 = 0.f, s2 = 0.f;
                #pragma unroll
                for (int nt = 0; nt < 4; ++nt) {
                    const int e = nt * 16 + lr;
                    float v = acc4[nt][i] + xs[(r << 6) + (e ^ ((r & 7) << 3))];
                    y[nt] = v; s1 += v; s2 += v * v;
                }
                #pragma unroll
                for (int d = 1; d < 16; d <<= 1) { s1 += __shfl_xor(s1, d, 64); s2 += __shfl_xor(s2, d, 64); }
                const float mu   = s1 * 0.015625f;
                const float var  = s2 * 0.015625f - mu * mu;
                const float rstd = rsqrtf(var + 1e-5f);
                #pragma unroll
                for (int nt = 0; nt < 4; ++nt) {
                    const int e = nt * 16 + lr;
                    float xn = (y[nt] - mu) * rstd * gg[nt] + bb2[nt];
                    const int sidx = (r << 6) + (e ^ ((r & 7) << 3));
                    xs[sidx]  = xn;
                    xbf[sidx] = f2bf(xn);
                }
            }
        }
        __syncthreads();
    }

    // ---- final: coalesced float4 store from xs (unswizzle) ----
    float* Op = out + (size_t)b * 8192;
    for (int i = tid; i < 2048; i += 512) {
        const int r  = i >> 4;
        const int e4 = (i & 15) << 2;
        const int se = e4 ^ ((r & 7) << 3);
        ((f32x4*)Op)[i] = *(const f32x4*)(xs + (r << 6) + se);
    }
}

extern "C" void kernel_launch(void* const* d_in, const int* in_sizes, int n_in,
                              void* d_out, int out_size, void* d_ws, size_t ws_size,
                              hipStream_t stream) {
    const float* G    = (const float*)d_in[0];
    const int*   mk   = (const int*)  d_in[1];
    const float* rv   = (const float*)d_in[2];
    const float* sw   = (const float*)d_in[3];
    const float* in_w = (const float*)d_in[4];
    const float* in_b = (const float*)d_in[5];
    const float* ow   = (const float*)d_in[6];
    const float* ob   = (const float*)d_in[7];
    const float* lg   = (const float*)d_in[8];
    const float* lb   = (const float*)d_in[9];
    float* out = (float*)d_out;
    unsigned short* wsw = (unsigned short*)d_ws;

    (void)in_sizes; (void)n_in; (void)out_size; (void)ws_size;

    prep_weights<<<dim3(64), dim3(256), 0, stream>>>(in_w, ow, wsw);

    hipFuncSetAttribute(reinterpret_cast<const void*>(nwa_kernel),
                        hipFuncAttributeMaxDynamicSharedMemorySize, SMEM_BYTES);
    nwa_kernel<<<dim3(4096), dim3(512), SMEM_BYTES, stream>>>(
        G, mk, rv, sw, wsw, in_b, ob, lg, lb, out);
}

// Round 4
// 1296.744 us; speedup vs baseline: 1.7814x; 1.7814x over previous
//
#include <hip/hip_runtime.h>
#include <stdint.h>

// NeighborWiseAttention fused kernel — R4 restructure.
// 1 block = 1 batch element, 256 threads (4 waves), both layers fused.
// Row-tiled M1: wave w owns rows w*32..w*32+31 end-to-end. Only k, v^T and
// small vectors in shared LDS; q/P/o transposed in-wave via private scratch.
// LDS 77.5KB -> 2 blocks/CU; 6 barriers total (was ~15).

typedef float f32x4 __attribute__((ext_vector_type(4)));
typedef short bf16x8 __attribute__((ext_vector_type(8)));

#define MFMA(a, b, c) __builtin_amdgcn_mfma_f32_16x16x32_bf16(a, b, c, 0, 0, 0)

#define SCALING 0.08838834764831845f  // HIDDEN^-0.5
#define SHIFTW 20.0f

// d_ws: wiT bf16 [2][384][64] @0 ; woT bf16 [2][64][128] @98304B

// LDS map (bytes):
//   kb   bf16[128][128] @ 0      32768  (k rows; init: aliased as xstage f32[128][64])
//   vtb  bf16[128][128] @ 32768  32768  (v^T [e][m])
//   scr  per-wave 2560B @ 65536  10240  (16x32 bf16 transpose bounce, row stride 40hw)
//   SW/MK/RX/RY/RZ/KS/VS f32[128] each @ 75776  3584
#define KB_OFF   0
#define VT_OFF   32768
#define SCR_OFF  65536
#define SW_OFF   75776
#define SMEM_BYTES 79360

__device__ __forceinline__ float bf2f(unsigned short u) {
    union { unsigned int u; float f; } v; v.u = ((unsigned int)u) << 16; return v.f;
}
__device__ __forceinline__ unsigned short f2bf(float f) {
    union { float f; unsigned int u; } v; v.f = f;
    unsigned int r = v.u + 0x7FFFu + ((v.u >> 16) & 1u);  // RNE
    return (unsigned short)(r >> 16);
}

// ---- prep: convert+transpose weights to bf16 in d_ws ----
__global__ void prep_weights(const float* __restrict__ in_w,
                             const float* __restrict__ out_w,
                             unsigned short* __restrict__ ws) {
    unsigned short* wiT = ws;                       // [2][384][64]
    unsigned short* woT = ws + 49152;               // [2][64][128]
    const int gid = blockIdx.x * blockDim.x + threadIdx.x;
    for (int i = gid; i < 49152; i += gridDim.x * blockDim.x) {
        const int l = i / 24576, rem = i % 24576;
        const int c = rem / 64, k = rem % 64;
        wiT[i] = f2bf(in_w[l * 24576 + k * 384 + c]);
    }
    for (int j = gid; j < 16384; j += gridDim.x * blockDim.x) {
        const int l = j / 8192, rem = j % 8192;
        const int e = rem / 128, k = rem % 128;
        woT[j] = f2bf(out_w[l * 8192 + k * 64 + e]);
    }
}

__global__ __launch_bounds__(256, 2)
void nwa_kernel(const float* __restrict__ G, const int* __restrict__ nmask,
                const float* __restrict__ rvec, const float* __restrict__ swg,
                const unsigned short* __restrict__ wsw,
                const float* __restrict__ in_b,
                const float* __restrict__ out_b,
                const float* __restrict__ ln_g, const float* __restrict__ ln_b,
                float* __restrict__ out)
{
    extern __shared__ __align__(16) char smem[];
    float* xst          = (float*)(smem + KB_OFF);           // init alias
    unsigned short* kb  = (unsigned short*)(smem + KB_OFF);
    unsigned short* vtb = (unsigned short*)(smem + VT_OFF);
    float* SWv = (float*)(smem + SW_OFF);
    float* MKv = SWv + 128;  float* RXv = SWv + 256;  float* RYv = SWv + 384;
    float* RZv = SWv + 512;  float* KSv = SWv + 640;  float* VSv = SWv + 768;

    const int b    = blockIdx.x;
    const int tid  = threadIdx.x;
    const int w    = tid >> 6;     // wave 0..3
    const int lane = tid & 63;
    const int lg   = lane >> 4;    // 0..3
    const int lr   = lane & 15;    // 0..15
    const int scrb = SCR_OFF + w * 2560;   // per-wave scratch (2 tilesets of 1280B)

    // ---- stage x (f32, swizzled on 8-float granule) into xst; small vectors ----
    const float* Gp = G + (size_t)b * 8192;
    for (int i = tid; i < 2048; i += 256) {
        f32x4 v = ((const f32x4*)Gp)[i];
        const int r  = i >> 4;
        const int e4 = (i & 15) << 2;
        const int se = e4 ^ ((r & 7) << 3);
        *(f32x4*)(xst + (r << 6) + se) = v;
    }
    if (tid < 128) {
        SWv[tid] = swg[(size_t)b * 128 + tid];
        MKv[tid] = nmask[(size_t)b * 128 + tid] ? 1.0f : 0.0f;
        const float* rp = rvec + ((size_t)b * 128 + tid) * 3;
        RXv[tid] = rp[0]; RYv[tid] = rp[1]; RZv[tid] = rp[2];
    }
    __syncthreads();   // (A) xst + small ready

    // ---- x A-fragments + f32 residual into registers ----
    bf16x8 ax[2][2];
    #pragma unroll
    for (int rt = 0; rt < 2; ++rt)
        #pragma unroll
        for (int kt = 0; kt < 2; ++kt) {
            const int row = w * 32 + rt * 16 + lr;
            const int off = (kt * 32 + lg * 8) ^ ((row & 7) << 3);
            f32x4 u0 = *(const f32x4*)(xst + (row << 6) + off);
            f32x4 u1 = *(const f32x4*)(xst + (row << 6) + off + 4);
            bf16x8 h;
            #pragma unroll
            for (int j = 0; j < 4; ++j) { h[j] = (short)f2bf(u0[j]); h[4 + j] = (short)f2bf(u1[j]); }
            ax[rt][kt] = h;
        }
    float res[2][4][4];
    #pragma unroll
    for (int rt = 0; rt < 2; ++rt)
        #pragma unroll
        for (int ect = 0; ect < 4; ++ect)
            #pragma unroll
            for (int i = 0; i < 4; ++i) {
                const int row = w * 32 + rt * 16 + lg * 4 + i;
                const int e   = ect * 16 + lr;
                res[rt][ect][i] = xst[(row << 6) + (e ^ ((row & 7) << 3))];
            }
    __syncthreads();   // (B) all xst reads done; kb region may be overwritten

    #pragma unroll 1
    for (int l = 0; l < 2; ++l) {
        const unsigned short* wiT = wsw + l * 24576;          // bf16 [384][64]
        const unsigned short* woT = wsw + 49152 + l * 8192;   // bf16 [64][128]
        const float* bi  = in_b  + l * 384;
        const float* bo  = out_b + l * 64;
        const float* lgp = ln_g  + l * 64;
        const float* lbp = ln_b  + l * 64;

        // ================= M1: qkv rows (own 32) x 384 cols =================
        bf16x8 aq[2][4];
        float qs_[2][4];
        {   // ---- q: col-tiles 0..7, keep in regs via transpose bounce ----
            float qss[2][4] = {{0,0,0,0},{0,0,0,0}};
            #pragma unroll
            for (int pp = 0; pp < 4; ++pp) {
                f32x4 acc[2][2];
                #pragma unroll
                for (int t = 0; t < 2; ++t) {
                    const int c = (pp * 2 + t) * 16 + lr;
                    bf16x8 b0 = *(const bf16x8*)(wiT + c * 64 + lg * 8);
                    bf16x8 b1 = *(const bf16x8*)(wiT + c * 64 + 32 + lg * 8);
                    const float bias = bi[c];
                    #pragma unroll
                    for (int rt = 0; rt < 2; ++rt) {
                        f32x4 a = { bias, bias, bias, bias };
                        a = MFMA(ax[rt][0], b0, a);
                        a = MFMA(ax[rt][1], b1, a);
                        acc[t][rt] = a;
                    }
                }
                #pragma unroll
                for (int rt = 0; rt < 2; ++rt) {
                    unsigned short* scr = (unsigned short*)(smem + scrb + rt * 1280);
                    #pragma unroll
                    for (int t = 0; t < 2; ++t)
                        #pragma unroll
                        for (int i = 0; i < 4; ++i) {
                            qss[rt][i] += acc[t][rt][i] * acc[t][rt][i];
                            scr[(lg * 4 + i) * 40 + t * 16 + lr] = f2bf(acc[t][rt][i]);
                        }
                    aq[rt][pp] = *(const bf16x8*)(scr + lr * 40 + lg * 8);
                }
            }
            #pragma unroll
            for (int rt = 0; rt < 2; ++rt)
                #pragma unroll
                for (int i = 0; i < 4; ++i) {
                    float s = qss[rt][i];
                    s += __shfl_xor(s, 1, 64); s += __shfl_xor(s, 2, 64);
                    s += __shfl_xor(s, 4, 64); s += __shfl_xor(s, 8, 64);
                    qs_[rt][i] = SCALING / fmaxf(sqrtf(s), 1e-12f);
                }
        }
        {   // ---- k: col-tiles 8..15 -> kb LDS + KS ----
            float kss[2][4] = {{0,0,0,0},{0,0,0,0}};
            #pragma unroll
            for (int pp = 0; pp < 4; ++pp) {
                #pragma unroll
                for (int t = 0; t < 2; ++t) {
                    const int cl = (pp * 2 + t) * 16 + lr;     // 0..127
                    const int c  = 128 + cl;
                    bf16x8 b0 = *(const bf16x8*)(wiT + c * 64 + lg * 8);
                    bf16x8 b1 = *(const bf16x8*)(wiT + c * 64 + 32 + lg * 8);
                    const float bias = bi[c];
                    #pragma unroll
                    for (int rt = 0; rt < 2; ++rt) {
                        f32x4 a = { bias, bias, bias, bias };
                        a = MFMA(ax[rt][0], b0, a);
                        a = MFMA(ax[rt][1], b1, a);
                        #pragma unroll
                        for (int i = 0; i < 4; ++i) {
                            kss[rt][i] += a[i] * a[i];
                            const int m = w * 32 + rt * 16 + lg * 4 + i;
                            kb[(m << 7) + (cl ^ ((m & 7) << 3))] = f2bf(a[i]);
                        }
                    }
                }
            }
            #pragma unroll
            for (int rt = 0; rt < 2; ++rt)
                #pragma unroll
                for (int i = 0; i < 4; ++i) {
                    float s = kss[rt][i];
                    s += __shfl_xor(s, 1, 64); s += __shfl_xor(s, 2, 64);
                    s += __shfl_xor(s, 4, 64); s += __shfl_xor(s, 8, 64);
                    if (lr == 0) KSv[w * 32 + rt * 16 + lg * 4 + i] = 1.0f / fmaxf(sqrtf(s), 1e-12f);
                }
        }
        {   // ---- v: col-tiles 16..23 -> vtb (transposed) + VS ----
            float vss[2][4] = {{0,0,0,0},{0,0,0,0}};
            #pragma unroll
            for (int pp = 0; pp < 4; ++pp) {
                #pragma unroll
                for (int t = 0; t < 2; ++t) {
                    const int e = (pp * 2 + t) * 16 + lr;      // 0..127
                    const int c = 256 + e;
                    bf16x8 b0 = *(const bf16x8*)(wiT + c * 64 + lg * 8);
                    bf16x8 b1 = *(const bf16x8*)(wiT + c * 64 + 32 + lg * 8);
                    const float bias = bi[c];
                    #pragma unroll
                    for (int rt = 0; rt < 2; ++rt) {
                        f32x4 a = { bias, bias, bias, bias };
                        a = MFMA(ax[rt][0], b0, a);
                        a = MFMA(ax[rt][1], b1, a);
                        #pragma unroll
                        for (int i = 0; i < 4; ++i) {
                            vss[rt][i] += a[i] * a[i];
                            const int m = w * 32 + rt * 16 + lg * 4 + i;
                            vtb[(e << 7) + (m ^ ((e & 7) << 3))] = f2bf(a[i]);
                        }
                    }
                }
            }
            #pragma unroll
            for (int rt = 0; rt < 2; ++rt)
                #pragma unroll
                for (int i = 0; i < 4; ++i) {
                    float s = vss[rt][i];
                    s += __shfl_xor(s, 1, 64); s += __shfl_xor(s, 2, 64);
                    s += __shfl_xor(s, 4, 64); s += __shfl_xor(s, 8, 64);
                    if (lr == 0) VSv[w * 32 + rt * 16 + lg * 4 + i] = 1.0f / fmaxf(sqrtf(s), 1e-12f);
                }
        }
        __syncthreads();   // (C) kb, vtb, KS, VS ready

        // row-side gate data for own rows
        float swr[2][4], mkr[2][4], rxr[2][4], ryr[2][4], rzr[2][4];
        #pragma unroll
        for (int rt = 0; rt < 2; ++rt)
            #pragma unroll
            for (int i = 0; i < 4; ++i) {
                const int n = w * 32 + rt * 16 + lg * 4 + i;
                swr[rt][i] = SWv[n]; mkr[rt][i] = MKv[n];
                rxr[rt][i] = RXv[n]; ryr[rt][i] = RYv[n]; rzr[rt][i] = RZv[n];
            }

        // ============ per row-tile: M2 -> softmax -> M3 -> M4 -> LN ============
        #pragma unroll
        for (int rt = 0; rt < 2; ++rt) {
            unsigned short* scr = (unsigned short*)(smem + scrb + rt * 1280);
            // ---- M2: S = q @ k^T ----
            float S[8][4];
            #pragma unroll
            for (int mt = 0; mt < 8; ++mt) {
                const int m = mt * 16 + lr;
                f32x4 a = { 0.f, 0.f, 0.f, 0.f };
                #pragma unroll
                for (int kt = 0; kt < 4; ++kt) {
                    bf16x8 bk = *(const bf16x8*)(kb + (m << 7) + ((kt * 32 + lg * 8) ^ ((m & 7) << 3)));
                    a = MFMA(aq[rt][kt], bk, a);
                }
                S[mt][0] = a[0]; S[mt][1] = a[1]; S[mt][2] = a[2]; S[mt][3] = a[3];
            }
            // ---- gated softmax (in-register) ----
            float mx[4] = { -1e30f, -1e30f, -1e30f, -1e30f };
            #pragma unroll
            for (int mt = 0; mt < 8; ++mt) {
                const int m = mt * 16 + lr;
                const float ksm = KSv[m], swm = SWv[m];
                #pragma unroll
                for (int i = 0; i < 4; ++i) {
                    float Lv = (S[mt][i] * qs_[rt][i] * ksm + SHIFTW) * (swr[rt][i] * swm) - SHIFTW;
                    S[mt][i] = Lv;
                    mx[i] = fmaxf(mx[i], Lv);
                }
            }
            #pragma unroll
            for (int i = 0; i < 4; ++i) {
                mx[i] = fmaxf(mx[i], __shfl_xor(mx[i], 1, 64));
                mx[i] = fmaxf(mx[i], __shfl_xor(mx[i], 2, 64));
                mx[i] = fmaxf(mx[i], __shfl_xor(mx[i], 4, 64));
                mx[i] = fmaxf(mx[i], __shfl_xor(mx[i], 8, 64));
            }
            float sm[4] = { 0.f, 0.f, 0.f, 0.f };
            #pragma unroll
            for (int mt = 0; mt < 8; ++mt)
                #pragma unroll
                for (int i = 0; i < 4; ++i) {
                    float e = __expf(S[mt][i] - mx[i]);
                    S[mt][i] = e; sm[i] += e;
                }
            #pragma unroll
            for (int i = 0; i < 4; ++i) {
                sm[i] += __shfl_xor(sm[i], 1, 64);
                sm[i] += __shfl_xor(sm[i], 2, 64);
                sm[i] += __shfl_xor(sm[i], 4, 64);
                sm[i] += __shfl_xor(sm[i], 8, 64);
                sm[i] = 1.0f / sm[i];
            }
            #pragma unroll
            for (int mt = 0; mt < 8; ++mt) {
                const int m = mt * 16 + lr;
                const float swm = SWv[m], rxm = RXv[m], rym = RYv[m], rzm = RZv[m], vsm = VSv[m];
                #pragma unroll
                for (int i = 0; i < 4; ++i) {
                    float ang = rxr[rt][i] * rxm + ryr[rt][i] * rym + rzr[rt][i] * rzm;
                    S[mt][i] = S[mt][i] * sm[i] * mkr[rt][i] * (swr[rt][i] * swm) * ang * vsm;
                }
            }
            // ---- P -> A-frags (in-wave transpose) ----
            bf16x8 ap[4];
            #pragma unroll
            for (int j = 0; j < 4; ++j) {
                #pragma unroll
                for (int t = 0; t < 2; ++t)
                    #pragma unroll
                    for (int i = 0; i < 4; ++i)
                        scr[(lg * 4 + i) * 40 + t * 16 + lr] = f2bf(S[2 * j + t][i]);
                ap[j] = *(const bf16x8*)(scr + lr * 40 + lg * 8);
            }
            // ---- M3: o = P @ v ----
            f32x4 oacc[8];
            #pragma unroll
            for (int et = 0; et < 8; ++et) {
                const int e = et * 16 + lr;
                f32x4 a = { 0.f, 0.f, 0.f, 0.f };
                #pragma unroll
                for (int kt = 0; kt < 4; ++kt) {
                    bf16x8 bv = *(const bf16x8*)(vtb + (e << 7) + ((kt * 32 + lg * 8) ^ ((e & 7) << 3)));
                    a = MFMA(ap[kt], bv, a);
                }
                oacc[et] = a;
            }
            // ---- o -> A-frags ----
            bf16x8 ao[4];
            #pragma unroll
            for (int j = 0; j < 4; ++j) {
                #pragma unroll
                for (int t = 0; t < 2; ++t)
                    #pragma unroll
                    for (int i = 0; i < 4; ++i)
                        scr[(lg * 4 + i) * 40 + t * 16 + lr] = f2bf(oacc[2 * j + t][i]);
                ao[j] = *(const bf16x8*)(scr + lr * 40 + lg * 8);
            }
            // ---- M4: out = o @ woT + bo ----
            f32x4 acc4[4];
            #pragma unroll
            for (int ect = 0; ect < 4; ++ect) {
                const int e = ect * 16 + lr;
                const float bias = bo[e];
                f32x4 a = { bias, bias, bias, bias };
                #pragma unroll
                for (int kt = 0; kt < 4; ++kt) {
                    bf16x8 bw = *(const bf16x8*)(woT + e * 128 + kt * 32 + lg * 8);
                    a = MFMA(ao[kt], bw, a);
                }
                acc4[ect] = a;
            }
            // ---- residual + LayerNorm ----
            float gg[4], bb2[4];
            #pragma unroll
            for (int ect = 0; ect < 4; ++ect) { gg[ect] = lgp[ect * 16 + lr]; bb2[ect] = lbp[ect * 16 + lr]; }
            float xn[4][4];
            #pragma unroll
            for (int i = 0; i < 4; ++i) {
                float y[4]; float s1 = 0.f, s2 = 0.f;
                #pragma unroll
                for (int ect = 0; ect < 4; ++ect) {
                    float v = acc4[ect][i] + res[rt][ect][i];
                    y[ect] = v; s1 += v; s2 += v * v;
                }
                s1 += __shfl_xor(s1, 1, 64); s2 += __shfl_xor(s2, 1, 64);
                s1 += __shfl_xor(s1, 2, 64); s2 += __shfl_xor(s2, 2, 64);
                s1 += __shfl_xor(s1, 4, 64); s2 += __shfl_xor(s2, 4, 64);
                s1 += __shfl_xor(s1, 8, 64); s2 += __shfl_xor(s2, 8, 64);
                const float mu   = s1 * 0.015625f;
                const float var  = s2 * 0.015625f - mu * mu;
                const float rstd = rsqrtf(var + 1e-5f);
                #pragma unroll
                for (int ect = 0; ect < 4; ++ect) {
                    float v = (y[ect] - mu) * rstd * gg[ect] + bb2[ect];
                    xn[ect][i] = v;
                    res[rt][ect][i] = v;   // residual for next layer
                }
            }
            if (l == 0) {
                // rebuild x A-frags for next layer's M1
                #pragma unroll
                for (int kt = 0; kt < 2; ++kt) {
                    #pragma unroll
                    for (int t = 0; t < 2; ++t)
                        #pragma unroll
                        for (int i = 0; i < 4; ++i)
                            scr[(lg * 4 + i) * 40 + t * 16 + lr] = f2bf(xn[2 * kt + t][i]);
                    ax[rt][kt] = *(const bf16x8*)(scr + lr * 40 + lg * 8);
                }
            } else {
                // final store
                float* Op = out + (size_t)b * 8192;
                #pragma unroll
                for (int ect = 0; ect < 4; ++ect)
                    #pragma unroll
                    for (int i = 0; i < 4; ++i) {
                        const int n = w * 32 + rt * 16 + lg * 4 + i;
                        Op[n * 64 + ect * 16 + lr] = xn[ect][i];
                    }
            }
        }
        __syncthreads();   // (D) end of layer: kb/vtb/KS/VS reads complete
    }
}

extern "C" void kernel_launch(void* const* d_in, const int* in_sizes, int n_in,
                              void* d_out, int out_size, void* d_ws, size_t ws_size,
                              hipStream_t stream) {
    const float* G    = (const float*)d_in[0];
    const int*   mk   = (const int*)  d_in[1];
    const float* rv   = (const float*)d_in[2];
    const float* sw   = (const float*)d_in[3];
    const float* in_w = (const float*)d_in[4];
    const float* in_b = (const float*)d_in[5];
    const float* ow   = (const float*)d_in[6];
    const float* ob   = (const float*)d_in[7];
    const float* lg   = (const float*)d_in[8];
    const float* lb   = (const float*)d_in[9];
    float* out = (float*)d_out;
    unsigned short* wsw = (unsigned short*)d_ws;

    (void)in_sizes; (void)n_in; (void)out_size; (void)ws_size;

    prep_weights<<<dim3(64), dim3(256), 0, stream>>>(in_w, ow, wsw);

    hipFuncSetAttribute(reinterpret_cast<const void*>(nwa_kernel),
                        hipFuncAttributeMaxDynamicSharedMemorySize, SMEM_BYTES);
    nwa_kernel<<<dim3(4096), dim3(256), SMEM_BYTES, stream>>>(
        G, mk, rv, sw, wsw, in_b, ob, lg, lb, out);
}